// Round 2
// baseline (3016.747 us; speedup 1.0000x reference)
//
#include <hip/hip_runtime.h>

// multiplicativeNoise round 5: round-4 MFMA-RK4 structure, numerics repaired.
//
// Round-4 failed NaN. All addressing maps re-derived and example-traced OK;
// the unverified deltas were (1) v_cvt_pk_bf16_f32 inline asm (semantics not
// HW-verified here) and (2) type-punned wave-local vbuf write->read with no
// compiler fence. This round removes both: all bf16 packing uses the
// round-3-verified f2bf/pack2 bit ops, and the stage-vector store is followed
// by a compiler memory fence. Abuf is zero-initialized once per block so any
// residual addressing hole shows up as finite-wrong, not NaN.
//
// Structure (unchanged from round 4):
//  - A-build: M_e[n] = sum_k G[n][k] dw_e[k] via 16x16x32 bf16 MFMA, written
//    directly in MFMA-A-fragment order with XOR bank swizzle on chunk low bits.
//  - RK4 stage k = M v via MFMA: v replicated across B cols, split bf16
//    (hi+lo) so v-quant error ~2^-17; each lane owns one output row
//    (row = ((lane>>2)&3)<<4 | (lane>>4)<<2 | (lane&3), a bijection).
//  - 16 elems/block, wave == element, counting-sorted batch, early exit.

typedef __attribute__((ext_vector_type(8))) short short8;
typedef __attribute__((ext_vector_type(4))) float f32x4;
typedef __attribute__((ext_vector_type(4))) unsigned u32x4;

#define NSTEP 100
#define BATCH 16384
#define NCHUNK 1024            // BATCH / 16

__device__ __forceinline__ unsigned short f2bf(float f) {
  unsigned u = __float_as_uint(f);
  unsigned r = (u + 0x7FFFu + ((u >> 16) & 1u)) >> 16;   // RNE
  return (unsigned short)r;
}
__device__ __forceinline__ unsigned pack2(float a, float b) {
  return (unsigned)f2bf(a) | ((unsigned)f2bf(b) << 16);
}

__device__ __forceinline__ short8 mk8(unsigned a, unsigned b, unsigned c, unsigned d) {
  u32x4 u = {a, b, c, d};
  return __builtin_bit_cast(short8, u);
}

// packed (lo|hi<<16) words -> bf16 pairs
__device__ __forceinline__ unsigned phi2(unsigned w0, unsigned w1) {
  return (w0 >> 16) | (w1 & 0xffff0000u);      // (hi(w0), hi(w1))
}
__device__ __forceinline__ unsigned plo2(unsigned w0, unsigned w1) {
  return (w0 & 0xffffu) | (w1 << 16);          // (lo(w0), lo(w1))
}

__device__ __forceinline__ float pick4(f32x4 a, bool b1, bool b2) {
  float c0 = b2 ? a[2] : a[0];
  float c1 = b2 ? a[3] : a[1];
  return b1 ? c1 : c0;
}

// ---------------- fused prep ----------------
// block 0: idx + counting sort (LDS hist/offs/cur). blocks 1..1024: G swizzle
// into bf16 MFMA-A-fragment order (identical mapping to round 3's k_swz).
__global__ void __launch_bounds__(256) k_prep(
    const float* __restrict__ G, const float* __restrict__ tv,
    unsigned short* __restrict__ g2s, int* __restrict__ idxb,
    int* __restrict__ perm)
{
  if (blockIdx.x == 0) {
    __shared__ int hist[NSTEP];
    __shared__ int offs[NSTEP];
    __shared__ int cur[NSTEP];
    const int tid = threadIdx.x;
    for (int i = tid; i < NSTEP; i += 256) { hist[i] = 0; cur[i] = 0; }
    __syncthreads();
    for (int r = 0; r < 64; ++r) {
      int b = (r << 8) + tid;
      int ix = (int)truncf(100.0f * tv[b]);    // matches jnp.trunc in fp32
      ix = min(max(ix, 0), NSTEP - 1);
      idxb[b] = ix;
      atomicAdd(&hist[ix], 1);
    }
    __syncthreads();
    if (tid == 0) {
      int run = 0;
      for (int i = 0; i < NSTEP; ++i) { offs[i] = run; run += hist[i]; }
    }
    __syncthreads();
    for (int r = 0; r < 64; ++r) {
      int b = (r << 8) + tid;
      int ix = idxb[b];
      int pos = offs[ix] + atomicAdd(&cur[ix], 1);
      perm[pos] = b;
    }
  } else {
    int o  = ((blockIdx.x - 1) << 8) + threadIdx.x;   // 262144 outputs exactly
    int nt = o >> 10;
    int r2 = o & 1023;
    int l  = r2 >> 4;
    int cc = (r2 >> 3) & 1;
    int j  = r2 & 7;
    int n  = (nt << 4) + (l & 15);
    int k  = (cc << 5) + ((l >> 4) << 3) + j;
    g2s[o] = f2bf(G[(n << 6) + k]);
  }
}

// ---------------- main kernel ----------------

__global__ void __launch_bounds__(1024, 1) k_main(
    const float* __restrict__ y0, const float* __restrict__ dW,
    const unsigned short* __restrict__ G2S, const int* __restrict__ perm,
    const int* __restrict__ idxb, float* __restrict__ out)
{
  __shared__ __align__(16) unsigned short Abuf[16 * 4096];  // 128 KB, A-frag order
  __shared__ __align__(16) unsigned short dwst[1024];       // 2 KB dw frags
  __shared__ __align__(16) unsigned vbuf[16 * 64];          // 4 KB packed lo|hi bf16
  __shared__ int meta_b[16], meta_i[16], chunk_max;

  const int t = threadIdx.x;
  const int lane = t & 63;
  const int wave = t >> 6;                   // wave == element

  // zero Abuf once: any addressing hole reads 0 (finite), not stale garbage
  {
    u32x4 z = {0u, 0u, 0u, 0u};
    u32x4* ab = (u32x4*)Abuf;
#pragma unroll
    for (int i = 0; i < 8; ++i) ab[t + (i << 10)] = z;
  }

  // interleave chunk->block mapping so per-CU work (sorted step counts) balances
  int W = blockIdx.x;
  int c = (W & 1) ? (NCHUNK - 1 - (W >> 1)) : (W >> 1);

  if (t < 16) {
    int b = perm[(c << 4) + t];
    meta_b[t] = b;
    meta_i[t] = idxb[b];
  }
  __syncthreads();
  if (t == 0) {
    int m = 0;
    for (int e = 0; e < 16; ++e) m = max(m, meta_i[e]);
    chunk_max = m;
  }
  const int my_b = meta_b[wave];
  const int my_idx = meta_i[wave];

  const int q = lane >> 4;
  // lane <-> output-row bijection (swap q/t bit-fields)
  const int row = (((lane >> 2) & 3) << 4) | (q << 2) | (lane & 3);
  const bool br1 = lane & 1, br2 = lane & 2, bt1 = lane & 4, bt2 = lane & 8;

  unsigned* vb = &vbuf[wave << 6];
  const uint4* vq0 = (const uint4*)(vb + (q << 3));        // rows 8q..8q+7
  const uint4* vq1 = (const uint4*)(vb + 32 + (q << 3));   // rows 32+8q..+7

  float y = y0[(my_b << 6) + row];
  {
    unsigned hb = (unsigned)f2bf(y);
    float hif = __uint_as_float(hb << 16);
    vb[row] = (hb << 16) | (unsigned)f2bf(y - hif);  // hi16=bf16(y), lo16=bf16(resid)
  }
  __syncthreads();                           // chunk_max + Abuf zero visible
  const int nsteps = chunk_max + 1;

  const int di = ((lane >> 3) << 7) + (wave << 3) + (lane & 7);

  // A-build write constants: value M[i][j] (i = nt>>2, j = 16(nt&3)+4q+r)
  // goes to chunk L = (Gg<<4)|((tt&3)<<2)|(wave>>2) of frag-block
  // (t = tt>>2, c = (wave&3)>>1), byte-in-chunk 8(q&1)+2r;
  // chunk low-3 bits ^= (e&7)^(L>>3) (bank swizzle, matched on read).
  const int ee = lane & 15;
  const int qh = q & 1;
  const int qv = q >> 1;
  const int Gg = ((wave & 1) << 1) + qv;
  const int wbase = (ee << 13) + (((wave & 3) >> 1) << 10) + (Gg << 8)
                  + (((wave >> 2) & 3) << 4) + (qh << 3);
  const int wx0 = ((ee & 7) ^ (Gg << 1)) << 4;

  // RK4 fragment read base (element == wave), same swizzle: logical chunk = lane
  const unsigned swz_r = ((unsigned)((wave & 7) ^ ((lane >> 3) & 7))) << 4;
  const char* abase = (const char*)Abuf + (wave << 13)
                    + (((unsigned)(lane << 4)) ^ swz_r);

  float dv = dW[(my_b << 6) + lane];         // step-0 dw, prefetched

  for (int s = 0; s < nsteps; ++s) {
    // ---- stage dw (bf16, MFMA B-frag order), prefetch next step's dw
    dwst[di] = f2bf(dv);
    if (s + 1 < nsteps) dv = dW[(((s + 1) * BATCH + my_b) << 6) + lane];
    __syncthreads();

    // ---- A-build: M[n][e] = sum_k G[n][k] dw_e[k], stored in A-frag order
    {
      short8 b0 = *(const short8*)(&dwst[lane << 3]);         // k 0..31
      short8 b1 = *(const short8*)(&dwst[512 + (lane << 3)]); // k 32..63
#pragma unroll 4
      for (int tt = 0; tt < 16; ++tt) {
        int nt = wave + (tt << 4);
        const unsigned short* gp = &G2S[(nt << 10) + (lane << 4)];  // coalesced
        short8 g0 = *(const short8*)(gp);
        short8 g1 = *(const short8*)(gp + 8);
        f32x4 acc = {0.f, 0.f, 0.f, 0.f};
        acc = __builtin_amdgcn_mfma_f32_16x16x32_bf16(g0, b0, acc, 0, 0, 0);
        acc = __builtin_amdgcn_mfma_f32_16x16x32_bf16(g1, b1, acc, 0, 0, 0);
        int wbyte = (wbase + ((tt >> 2) << 11) + ((tt & 3) << 6))
                  ^ (wx0 ^ (((tt & 3) >> 1) << 4));
        *(uint2*)((char*)Abuf + wbyte) =
            make_uint2(pack2(acc[0], acc[1]), pack2(acc[2], acc[3]));
      }
    }
    __syncthreads();

    // ---- RK4 via MFMA: 8 conflict-free b128 frag loads, then 4 stages
    {
      short8 M00 = *(const short8*)(abase);          // row-tile 0, k 0..31
      short8 M01 = *(const short8*)(abase + 1024);   // row-tile 0, k 32..63
      short8 M10 = *(const short8*)(abase + 2048);
      short8 M11 = *(const short8*)(abase + 3072);
      short8 M20 = *(const short8*)(abase + 4096);
      short8 M21 = *(const short8*)(abase + 5120);
      short8 M30 = *(const short8*)(abase + 6144);
      short8 M31 = *(const short8*)(abase + 7168);

      auto stage_k = [&]() -> float {
        uint4 A0 = vq0[0], A1 = vq0[1], B0 = vq1[0], B1 = vq1[1];
        short8 h0 = mk8(phi2(A0.x, A0.y), phi2(A0.z, A0.w), phi2(A1.x, A1.y), phi2(A1.z, A1.w));
        short8 l0 = mk8(plo2(A0.x, A0.y), plo2(A0.z, A0.w), plo2(A1.x, A1.y), plo2(A1.z, A1.w));
        short8 h1 = mk8(phi2(B0.x, B0.y), phi2(B0.z, B0.w), phi2(B1.x, B1.y), phi2(B1.z, B1.w));
        short8 l1 = mk8(plo2(B0.x, B0.y), plo2(B0.z, B0.w), plo2(B1.x, B1.y), plo2(B1.z, B1.w));
        f32x4 a0 = {0.f, 0.f, 0.f, 0.f};
        f32x4 a1 = a0, a2 = a0, a3 = a0;
        a0 = __builtin_amdgcn_mfma_f32_16x16x32_bf16(M00, h0, a0, 0, 0, 0);
        a1 = __builtin_amdgcn_mfma_f32_16x16x32_bf16(M10, h0, a1, 0, 0, 0);
        a2 = __builtin_amdgcn_mfma_f32_16x16x32_bf16(M20, h0, a2, 0, 0, 0);
        a3 = __builtin_amdgcn_mfma_f32_16x16x32_bf16(M30, h0, a3, 0, 0, 0);
        a0 = __builtin_amdgcn_mfma_f32_16x16x32_bf16(M00, l0, a0, 0, 0, 0);
        a1 = __builtin_amdgcn_mfma_f32_16x16x32_bf16(M10, l0, a1, 0, 0, 0);
        a2 = __builtin_amdgcn_mfma_f32_16x16x32_bf16(M20, l0, a2, 0, 0, 0);
        a3 = __builtin_amdgcn_mfma_f32_16x16x32_bf16(M30, l0, a3, 0, 0, 0);
        a0 = __builtin_amdgcn_mfma_f32_16x16x32_bf16(M01, h1, a0, 0, 0, 0);
        a1 = __builtin_amdgcn_mfma_f32_16x16x32_bf16(M11, h1, a1, 0, 0, 0);
        a2 = __builtin_amdgcn_mfma_f32_16x16x32_bf16(M21, h1, a2, 0, 0, 0);
        a3 = __builtin_amdgcn_mfma_f32_16x16x32_bf16(M31, h1, a3, 0, 0, 0);
        a0 = __builtin_amdgcn_mfma_f32_16x16x32_bf16(M01, l1, a0, 0, 0, 0);
        a1 = __builtin_amdgcn_mfma_f32_16x16x32_bf16(M11, l1, a1, 0, 0, 0);
        a2 = __builtin_amdgcn_mfma_f32_16x16x32_bf16(M21, l1, a2, 0, 0, 0);
        a3 = __builtin_amdgcn_mfma_f32_16x16x32_bf16(M31, l1, a3, 0, 0, 0);
        // select this lane's own row: k[row] = a[t*][r*]
        float p0 = pick4(a0, br1, br2);
        float p1 = pick4(a1, br1, br2);
        float p2 = pick4(a2, br1, br2);
        float p3 = pick4(a3, br1, br2);
        float sl = bt1 ? p1 : p0;
        float sh = bt1 ? p3 : p2;
        return bt2 ? sh : sl;
      };

      auto wrv = [&](float v) {              // publish split-bf16 stage vector
        unsigned hb = (unsigned)f2bf(v);
        float hif = __uint_as_float(hb << 16);
        vb[row] = (hb << 16) | (unsigned)f2bf(v - hif);
        asm volatile("" ::: "memory");       // fence store vs next stage's reads
      };

      float k1 = stage_k();
      wrv(fmaf(0.5f, k1, y));
      float k2 = stage_k();
      wrv(fmaf(0.5f, k2, y));
      float k3 = stage_k();
      wrv(y + k3);
      float k4 = stage_k();
      float yn = fmaf(k1 + 2.f * k2 + 2.f * k3 + k4, (1.f / 6.f), y);
      if (s == my_idx) out[(my_b << 6) + row] = yn;
      y = yn;
      wrv(yn);                               // stage-1 vector for next step
    }
  }
}

// ---------------- launch ----------------

extern "C" void kernel_launch(void* const* d_in, const int* in_sizes, int n_in,
                              void* d_out, int out_size, void* d_ws, size_t ws_size,
                              hipStream_t stream) {
  const float* y0 = (const float*)d_in[0];
  const float* tv = (const float*)d_in[1];
  const float* G  = (const float*)d_in[2];
  const float* dW = (const float*)d_in[3];
  float* out = (float*)d_out;

  char* w = (char*)d_ws;
  unsigned short* g2s = (unsigned short*)w;          // 512 KB bf16 swizzled G
  int* idxb = (int*)(w + 524288);                    // 64 KB
  int* perm = (int*)(w + 524288 + 65536);            // 64 KB

  k_prep<<<1025, 256, 0, stream>>>(G, tv, g2s, idxb, perm);
  k_main<<<NCHUNK, 1024, 0, stream>>>(y0, dW, g2s, perm, idxb, out);
}